// Round 4
// baseline (2527.696 us; speedup 1.0000x reference)
//
#include <hip/hip_runtime.h>
#include <math.h>

// Problem constants (fixed by setup_inputs: B=8, n=256, s=256)
#define NCTRL 256          // control points
#define NA    259          // n + 3 (TPS system size)
#define NAUG  261          // + 2 rhs columns
#define APITCH 264         // padded row pitch (floats) for the augmented matrix
#define BATCH 8
#define SGRID 256
#define NB    32           // LU panel width
#define NPAN  9            // 8 full panels + 1 of width 3
#define SPITCH 232         // U12 stage pitch (>= max trailing cols 231)
#define PLP   33           // panL pitch (conflict-free column reads)
#define PBP   36           // panB pitch (16B-aligned rows for float4)

// ---------------------------------------------------------------------------
// Kernel 1: build the augmented TPS system per batch.
// ---------------------------------------------------------------------------
__global__ __launch_bounds__(256) void build_kernel(const float* __restrict__ src,
                                                    const float* __restrict__ dst,
                                                    float* __restrict__ A){
  const int b = blockIdx.x;
  const float* sb = src + b*NCTRL*2;
  const float* db = dst + b*NCTRL*2;
  float* Ab = A + (size_t)b*NA*APITCH;
  __shared__ float sx[NCTRL], sy[NCTRL];
  {
    int t = threadIdx.x;
    sx[t] = sb[2*t]; sy[t] = sb[2*t+1];
  }
  __syncthreads();
  const int total = NA*APITCH;
  for (int idx = threadIdx.x; idx < total; idx += 256){
    int r = idx / APITCH;
    int c = idx - r*APITCH;
    float v = 0.0f;
    if (r < NCTRL){
      if (c < NCTRL){
        float dx = sx[r] - sx[c];
        float dy = sy[r] - sy[c];
        v = sqrtf(fmaf(dx, dx, dy*dy));
      } else if (c == NCTRL)   v = 1.0f;
      else if (c == NCTRL+1)   v = sx[r];
      else if (c == NCTRL+2)   v = sy[r];
      else if (c == NA)        v = db[2*r];
      else if (c == NA+1)      v = db[2*r+1];
    } else if (c < NCTRL){
      v = (r == NCTRL) ? 1.0f : ((r == NCTRL+1) ? sx[c] : sy[c]);
    }
    Ab[idx] = v;
  }
}

// ---------------------------------------------------------------------------
// Single-wave register-resident panel factorization with LOGICAL pivoting.
// Lane l, slot r owns panel row (64*r + l). No barriers, no LDS round-trips:
// argmax via shfl_xor (all lanes learn the winner), pivot row via static
// slot-select + shfl. Pivot rows are only RECORDED (gq[]); rows never move.
// On exit panL holds the packed L\U in ORIGINAL slot order.
// ---------------------------------------------------------------------------
template<int RPL, int NBC>
__device__ __forceinline__ void panel_factor_wave0(
    const int rows, const int lane, float (*panL)[PLP], int* __restrict__ gq)
{
  float rr[RPL][NBC];
  unsigned valid = 0, done = 0;
  #pragma unroll
  for (int r = 0; r < RPL; ++r){
    int gl = 64*r + lane;
    if (gl < rows){
      valid |= (1u << r);
      #pragma unroll
      for (int c = 0; c < NBC; ++c) rr[r][c] = panL[gl][c];
    } else {
      #pragma unroll
      for (int c = 0; c < NBC; ++c) rr[r][c] = 0.0f;
    }
  }

  #pragma unroll
  for (int j = 0; j < NBC; ++j){
    // --- candidate (value, slot-index) per lane ---
    float lv = -1.0f; int lq = lane;
    #pragma unroll
    for (int r = 0; r < RPL; ++r){
      bool act = ((valid >> r) & 1) && !((done >> r) & 1);
      float a = act ? fabsf(rr[r][j]) : -1.0f;
      int q = (r << 6) | lane;
      if (a > lv || (a == lv && q < lq)){ lv = a; lq = q; }
    }
    // --- wave argmax: all lanes converge to the same winner ---
    #pragma unroll
    for (int off = 32; off; off >>= 1){
      float ov = __shfl_xor(lv, off);
      int   oq = __shfl_xor(lq, off);
      if (ov > lv || (ov == lv && oq < lq)){ lv = ov; lq = oq; }
    }
    const int src_lane = lq & 63, src_r = lq >> 6;
    // --- extract pivot row (cols j..NBC-1): static slot select + shfl ---
    float pr[NBC];
    #pragma unroll
    for (int c = j; c < NBC; ++c){
      float tmp = rr[0][c];
      #pragma unroll
      for (int r = 1; r < RPL; ++r) tmp = (src_r == r) ? rr[r][c] : tmp;
      pr[c] = __shfl(tmp, src_lane);
    }
    if (lane == 0) gq[j] = lq;           // record pivot slot
    if (lane == src_lane) done |= (1u << src_r);
    const float rpiv = 1.0f / pr[j];
    // --- rank-1 update, fully in registers ---
    #pragma unroll
    for (int r = 0; r < RPL; ++r){
      bool act = ((valid >> r) & 1) && !((done >> r) & 1);
      float f = act ? (rr[r][j] * rpiv) : 0.0f;
      rr[r][j] = act ? f : rr[r][j];
      #pragma unroll
      for (int c = j+1; c < NBC; ++c)
        rr[r][c] = fmaf(-f, pr[c], rr[r][c]);
    }
  }

  // --- write packed panel back (original slot order) ---
  #pragma unroll
  for (int r = 0; r < RPL; ++r){
    int gl = 64*r + lane;
    if (gl < rows){
      #pragma unroll
      for (int c = 0; c < NBC; ++c) panL[gl][c] = rr[r][c];
    }
  }
}

// ---------------------------------------------------------------------------
// Kernel 2: blocked LU, one block per batch, 512 threads. Logical pivoting
// via rowmap[] (LDS) — rows are never physically permuted in global memory.
// ---------------------------------------------------------------------------
__global__ __launch_bounds__(512, 2) void lu_blocked(float* __restrict__ A,
                                                     float* __restrict__ wv){
  const int b = blockIdx.x;
  float* Ab = A + (size_t)b*NA*APITCH;
  const int tid  = threadIdx.x;
  const int lane = tid & 63;
  const int wid  = tid >> 6;

  __shared__ float panL[NA][PLP];     // 34.2 KB — raw/factored panel (slot order)
  __shared__ float panB[NA][PBP];     // 37.3 KB — gathered panel (new-logical order)
  __shared__ float stg[NB][SPITCH];   // 29.7 KB — U12
  __shared__ float xs2[2*NA];
  __shared__ float tsum[NB][2];
  __shared__ int   rowmap[NA];        // logical -> physical global row
  __shared__ int   newloc[NA];        // panel-local old-logical -> new-logical
  __shared__ int   donearr[NA];
  __shared__ int   gq[NB];
  __shared__ int   scanw[8];

  for (int i = tid; i < NA; i += 512) rowmap[i] = i;
  __syncthreads();

  for (int p = 0; p < NPAN; ++p){
    const int k0   = p*NB;
    const int nb   = (NA - k0 < NB) ? (NA - k0) : NB;
    const int rows = NA - k0;
    const int ctop = k0 + nb;
    const int tc   = NAUG - ctop;     // trailing cols incl 2 rhs (>=2 always)

    // ---- stage panel into panL (coalesced global reads) ----
    if (nb == NB){
      for (int idx = tid; idx < rows*8; idx += 512){
        int q = idx >> 3, quad = idx & 7;
        const float* g = Ab + (size_t)rowmap[k0+q]*APITCH + k0 + 4*quad;
        float4 v = *(const float4*)g;
        panL[q][4*quad+0] = v.x; panL[q][4*quad+1] = v.y;
        panL[q][4*quad+2] = v.z; panL[q][4*quad+3] = v.w;
      }
    } else {
      for (int idx = tid; idx < rows*nb; idx += 512){
        int q = idx / 3, c = idx - q*3;
        panL[q][c] = Ab[(size_t)rowmap[k0+q]*APITCH + k0 + c];
      }
    }
    __syncthreads();

    // ---- wave0: barrier-free register factor ----
    if (wid == 0){
      if (p <= 2)      panel_factor_wave0<5,NB>(rows, lane, panL, gq);
      else if (p <= 6) panel_factor_wave0<3,NB>(rows, lane, panL, gq);
      else if (p == 7) panel_factor_wave0<1,NB>(rows, lane, panL, gq);
      else             panel_factor_wave0<1,3>(rows, lane, panL, gq);
    }
    __syncthreads();

    // ---- pivot flags ----
    for (int t = tid; t < rows; t += 512) donearr[t] = 0;
    __syncthreads();
    if (tid < nb) donearr[gq[tid]] = 1;
    __syncthreads();

    // ---- prefix-sum ranks -> newloc ----
    {
      int x = (tid < rows) ? (1 - donearr[tid]) : 0;
      int s = x;
      #pragma unroll
      for (int off = 1; off < 64; off <<= 1){
        int o = __shfl_up(s, off);
        if (lane >= off) s += o;
      }
      if (lane == 63) scanw[wid] = s;
      __syncthreads();
      int base = 0;
      for (int w = 0; w < wid; ++w) base += scanw[w];
      if (tid < rows && !donearr[tid]) newloc[tid] = nb + base + s - x;
      if (tid < nb) newloc[gq[tid]] = tid;
      __syncthreads();
    }

    // ---- rowmap permute + panB gather (new-logical order) ----
    int myold = (tid < rows) ? rowmap[k0 + tid] : 0;
    __syncthreads();
    if (tid < rows) rowmap[k0 + newloc[tid]] = myold;
    if (nb == NB){
      for (int idx = tid; idx < rows*NB; idx += 512){
        int q = idx >> 5, c = idx & 31;
        panB[newloc[q]][c] = panL[q][c];
      }
    } else {
      for (int idx = tid; idx < rows*3; idx += 512){
        int q = idx / 3, c = idx - q*3;
        panB[newloc[q]][c] = panL[q][c];
      }
    }
    __syncthreads();

    // ---- U11/L11 write-back (back-sub reads upper part later) ----
    for (int idx = tid; idx < nb*nb; idx += 512){
      int r = (nb == NB) ? (idx >> 5) : (idx / 3);
      int c = (nb == NB) ? (idx & 31) : (idx - r*3);
      Ab[(size_t)rowmap[k0+r]*APITCH + k0 + c] = panB[r][c];
    }

    // ---- TRSM: U12 = L11^{-1} A12 (incl rhs cols) ----
    if (nb == NB){
      for (int c = tid; c < tc; c += 512){
        float u[NB];
        #pragma unroll
        for (int m = 0; m < NB; ++m) u[m] = Ab[(size_t)rowmap[k0+m]*APITCH + ctop + c];
        #pragma unroll
        for (int m = 0; m < NB; ++m){
          #pragma unroll
          for (int jj = m+1; jj < NB; ++jj)
            u[jj] = fmaf(-panB[jj][m], u[m], u[jj]);
        }
        #pragma unroll
        for (int m = 0; m < NB; ++m){
          Ab[(size_t)rowmap[k0+m]*APITCH + ctop + c] = u[m];
          stg[m][c] = u[m];
        }
      }
    } else {
      for (int c = tid; c < tc; c += 512){
        float u0 = Ab[(size_t)rowmap[k0+0]*APITCH + ctop + c];
        float u1 = Ab[(size_t)rowmap[k0+1]*APITCH + ctop + c];
        float u2 = Ab[(size_t)rowmap[k0+2]*APITCH + ctop + c];
        u1 = fmaf(-panB[1][0], u0, u1);
        u2 = fmaf(-panB[2][0], u0, u2);
        u2 = fmaf(-panB[2][1], u1, u2);
        Ab[(size_t)rowmap[k0+0]*APITCH + ctop + c] = u0;
        Ab[(size_t)rowmap[k0+1]*APITCH + ctop + c] = u1;
        Ab[(size_t)rowmap[k0+2]*APITCH + ctop + c] = u2;
      }
    }
    __syncthreads();

    // ---- GEMM: A22 -= L21 * U12, 4x4 register tiles, float4 LDS reads ----
    const int R = rows - nb;
    if (R > 0){
      const int rt = (R + 3) >> 2, ct = (tc + 3) >> 2;
      for (int t = tid; t < rt*ct; t += 512){
        int tr = t / ct, tcc = t - tr*ct;
        int i0 = nb + tr*4, c0 = tcc*4;
        const bool full = (c0 + 4 <= tc);
        int ir[4], grow[4];
        #pragma unroll
        for (int r = 0; r < 4; ++r){
          int i = i0 + r;
          ir[r]   = (i < rows) ? i : (rows - 1);
          grow[r] = rowmap[k0 + ir[r]];
        }
        float acc[4][4];
        #pragma unroll
        for (int r = 0; r < 4; ++r){
          const float* g = Ab + (size_t)grow[r]*APITCH + ctop + c0;
          bool rowok = (i0 + r < rows);
          if (rowok && full){
            float4 v = *(const float4*)g;
            acc[r][0]=v.x; acc[r][1]=v.y; acc[r][2]=v.z; acc[r][3]=v.w;
          } else {
            #pragma unroll
            for (int c = 0; c < 4; ++c)
              acc[r][c] = (rowok && (c0 + c < tc)) ? g[c] : 0.0f;
          }
        }
        #pragma unroll
        for (int mq = 0; mq < NB/4; ++mq){
          float4 lv[4];
          #pragma unroll
          for (int r = 0; r < 4; ++r)
            lv[r] = *(const float4*)&panB[ir[r]][4*mq];
          #pragma unroll
          for (int mi = 0; mi < 4; ++mi){
            float4 uv = *(const float4*)&stg[4*mq + mi][c0];
            #pragma unroll
            for (int r = 0; r < 4; ++r){
              float l = (mi==0) ? lv[r].x : (mi==1) ? lv[r].y : (mi==2) ? lv[r].z : lv[r].w;
              acc[r][0] = fmaf(-l, uv.x, acc[r][0]);
              acc[r][1] = fmaf(-l, uv.y, acc[r][1]);
              acc[r][2] = fmaf(-l, uv.z, acc[r][2]);
              acc[r][3] = fmaf(-l, uv.w, acc[r][3]);
            }
          }
        }
        #pragma unroll
        for (int r = 0; r < 4; ++r){
          if (i0 + r < rows){
            float* g = Ab + (size_t)grow[r]*APITCH + ctop + c0;
            if (full){
              float4 v; v.x=acc[r][0]; v.y=acc[r][1]; v.z=acc[r][2]; v.w=acc[r][3];
              *(float4*)g = v;
            } else {
              #pragma unroll
              for (int c = 0; c < 4; ++c)
                if (c0 + c < tc) g[c] = acc[r][c];
            }
          }
        }
      }
    }
    __syncthreads();
  }

  // ======================== blocked back-substitution ========================
  for (int bp = NPAN-1; bp >= 0; --bp){
    const int k0 = bp*NB;
    const int nb = (NA - k0 < NB) ? (NA - k0) : NB;
    const int cs = k0 + nb;
    const int below = NA - cs;

    {
      int g = tid >> 3, sub = tid & 7;
      int row = g >> 1, ch = g & 1;
      float s = 0.0f;
      if (row < nb){
        const size_t rbase = (size_t)rowmap[k0+row]*APITCH;
        if (sub == 0) s = Ab[rbase + NA + ch];
        for (int c = sub; c < below; c += 8)
          s -= Ab[rbase + cs + c] * xs2[(cs + c)*2 + ch];
      }
      s += __shfl_xor(s, 4); s += __shfl_xor(s, 2); s += __shfl_xor(s, 1);
      if (row < nb && sub == 0) tsum[row][ch] = s;
    }
    for (int idx = tid; idx < nb*nb; idx += 512){
      int r = idx / nb, c = idx - r*nb;
      panB[r][c] = Ab[(size_t)rowmap[k0+r]*APITCH + k0 + c];
    }
    __syncthreads();
    if (wid == 0){
      int j = lane >> 1, ch = lane & 1;
      float tval = (j < nb) ? tsum[j][ch] : 0.0f;
      for (int k = nb-1; k >= 0; --k){
        float tk = __shfl(tval, 2*k + ch);
        float xk = tk / panB[k][k];
        if (j <  k) tval = fmaf(-panB[j][k], xk, tval);
        if (j == k) tval = xk;
      }
      if (j < nb) xs2[(k0+j)*2 + ch] = tval;
    }
    __syncthreads();
  }

  for (int i = tid; i < NA; i += 512){
    wv[((size_t)b*NA + i)*2 + 0] = xs2[i*2+0];
    wv[((size_t)b*NA + i)*2 + 1] = xs2[i*2+1];
  }
}

// ---------------------------------------------------------------------------
// Kernel 3: evaluate the warp on the s x s grid.
// ---------------------------------------------------------------------------
__global__ __launch_bounds__(256) void eval_kernel(const float* __restrict__ src,
                                                   const float* __restrict__ wv,
                                                   float* __restrict__ out){
  const int b  = blockIdx.x >> 8;
  const int yi = blockIdx.x & 255;
  const int xi = threadIdx.x;
  __shared__ float sx[NCTRL], sy[NCTRL], wx[NCTRL], wy[NCTRL];
  const float* sb = src + b*NCTRL*2;
  const float* wb = wv + (size_t)b*NA*2;
  sx[xi] = sb[2*xi]; sy[xi] = sb[2*xi+1];
  wx[xi] = wb[2*xi]; wy[xi] = wb[2*xi+1];
  __syncthreads();

  const float step = 2.0f/255.0f;
  const float gx = -1.0f + step*(float)xi;
  const float gy = -1.0f + step*(float)yi;

  float accx = wb[512] + wb[514]*gx + wb[516]*gy;
  float accy = wb[513] + wb[515]*gx + wb[517]*gy;

  #pragma unroll 8
  for (int j = 0; j < NCTRL; ++j){
    float dx = gx - sx[j];
    float dy = gy - sy[j];
    float r = sqrtf(fmaf(dx, dx, dy*dy));
    accx = fmaf(r, wx[j], accx);
    accy = fmaf(r, wy[j], accy);
  }
  out[((size_t)(b*2    )*SGRID + yi)*SGRID + xi] = accx;
  out[((size_t)(b*2 + 1)*SGRID + yi)*SGRID + xi] = accy;
}

// ---------------------------------------------------------------------------
extern "C" void kernel_launch(void* const* d_in, const int* in_sizes, int n_in,
                              void* d_out, int out_size, void* d_ws, size_t ws_size,
                              hipStream_t stream) {
  const float* src = (const float*)d_in[0];
  const float* dst = (const float*)d_in[1];
  float* out = (float*)d_out;

  const size_t matElems = (size_t)BATCH*NA*APITCH;
  float* A  = (float*)d_ws;
  float* wv = A + matElems;

  build_kernel<<<BATCH, 256, 0, stream>>>(src, dst, A);
  lu_blocked<<<BATCH, 512, 0, stream>>>(A, wv);
  eval_kernel<<<BATCH*SGRID, 256, 0, stream>>>(src, wv, out);
}

// Round 5
// 1031.967 us; speedup vs baseline: 2.4494x; 2.4494x over previous
//
#include <hip/hip_runtime.h>
#include <math.h>

// Problem constants (fixed by setup_inputs: B=8, n=256, s=256)
#define NCTRL 256          // control points
#define NA    259          // n + 3 (TPS system size)
#define NAUG  261          // + 2 rhs columns
#define APITCH 264         // padded row pitch (floats) for the augmented matrix
#define BATCH 8
#define SGRID 256
#define NB    32           // LU panel width
#define NPAN  9            // 8 full panels + 1 of width 3
#define SPITCH 232         // stage pitch (>= max trailing cols 229)
#define PPITCH 36          // pan pitch: 36*4=144 bytes, 16B-aligned rows

// ---------------------------------------------------------------------------
// Kernel 1: build the augmented TPS system per batch.
// ---------------------------------------------------------------------------
__global__ __launch_bounds__(256) void build_kernel(const float* __restrict__ src,
                                                    const float* __restrict__ dst,
                                                    float* __restrict__ A){
  const int b = blockIdx.x;
  const float* sb = src + b*NCTRL*2;
  const float* db = dst + b*NCTRL*2;
  float* Ab = A + (size_t)b*NA*APITCH;
  __shared__ float sx[NCTRL], sy[NCTRL];
  {
    int t = threadIdx.x;
    sx[t] = sb[2*t]; sy[t] = sb[2*t+1];
  }
  __syncthreads();
  const int total = NA*APITCH;
  for (int idx = threadIdx.x; idx < total; idx += 256){
    int r = idx / APITCH;
    int c = idx - r*APITCH;
    float v = 0.0f;
    if (r < NCTRL){
      if (c < NCTRL){
        float dx = sx[r] - sx[c];
        float dy = sy[r] - sy[c];
        v = sqrtf(fmaf(dx, dx, dy*dy));
      } else if (c == NCTRL)   v = 1.0f;
      else if (c == NCTRL+1)   v = sx[r];
      else if (c == NCTRL+2)   v = sy[r];
      else if (c == NA)        v = db[2*r];
      else if (c == NA+1)      v = db[2*r+1];
    } else if (c < NCTRL){
      v = (r == NCTRL) ? 1.0f : ((r == NCTRL+1) ? sx[c] : sy[c]);
    }
    Ab[idx] = v;
  }
}

// ---------------------------------------------------------------------------
// Kernel 2: blocked right-looking LU with partial pivoting, one block/batch,
// 512 threads. Panel factorization runs on WAVE 0 ONLY, entirely on the LDS
// panel: argmax via shfl (no LDS round-trip), physical row swap in LDS,
// float4-vectorized rank-1 update. Zero __syncthreads per ministep — in-wave
// DS ordering + wave_barrier/sched_barrier compiler fences (rule #18).
// ---------------------------------------------------------------------------
__global__ __launch_bounds__(512) void lu_blocked(float* __restrict__ A,
                                                  float* __restrict__ wv){
  const int b = blockIdx.x;
  float* Ab = A + (size_t)b*NA*APITCH;
  const int tid  = threadIdx.x;
  const int lane = tid & 63;
  const int wid  = tid >> 6;

  __shared__ float pan[NA][PPITCH];    // 37.3 KB — LDS panel (16B-aligned rows)
  __shared__ float stg[2*NB][SPITCH];  // 59.4 KB — laswp stage / U12
  __shared__ float xs2[2*NA];
  __shared__ float tsum[NB][2];
  __shared__ int   perm[NA];
  __shared__ int   pivloc[NB];
  __shared__ int   mvlist[2*NB];
  __shared__ int   mvcnt;

  // ======================== factorization ========================
  for (int p = 0; p < NPAN; ++p){
    const int k0   = p*NB;
    const int nb   = (NA - k0 < NB) ? (NA - k0) : NB;
    const int rows = NA - k0;
    const int ctop = k0 + nb;          // first trailing column
    const int tc   = NAUG - ctop;      // trailing cols incl 2 rhs

    // ---- stage panel into LDS (float4, coalesced) ----
    if (nb == NB){
      for (int idx = tid; idx < rows*8; idx += 512){
        int i = idx >> 3, q = idx & 7;
        float4 v = *(const float4*)(Ab + (size_t)(k0+i)*APITCH + k0 + 4*q);
        *(float4*)&pan[i][4*q] = v;
      }
    } else {
      for (int idx = tid; idx < rows*nb; idx += 512){
        int i = idx / 3, c = idx - i*3;
        pan[i][c] = Ab[(size_t)(k0+i)*APITCH + k0 + c];
      }
    }
    if (tid == 0) mvcnt = 0;
    __syncthreads();

    // ---- wave0: barrier-free panel factorization on LDS ----
    if (wid == 0){
      if (nb == NB){
        for (int j = 0; j < NB; ++j){
          // pivot search: strided LDS column read + shfl argmax
          float bv = -1.0f; int bi = j;
          for (int i = j + lane; i < rows; i += 64){
            float a = fabsf(pan[i][j]);
            if (a > bv){ bv = a; bi = i; }
          }
          #pragma unroll
          for (int off = 32; off; off >>= 1){
            float ov = __shfl_xor(bv, off);
            int   oi = __shfl_xor(bi, off);
            if (ov > bv || (ov == bv && oi < bi)){ bv = ov; bi = oi; }
          }
          // all lanes agree on bi
          if (lane == 0) pivloc[j] = bi;
          if (bi != j && lane < 8){    // swap rows j<->bi, one float4 per lane
            float4 tj = *(float4*)&pan[j][4*lane];
            float4 tb = *(float4*)&pan[bi][4*lane];
            *(float4*)&pan[j][4*lane]  = tb;
            *(float4*)&pan[bi][4*lane] = tj;
          }
          __builtin_amdgcn_wave_barrier();
          __builtin_amdgcn_sched_barrier(0);
          // pivot row -> registers (static float4 indexing)
          float4 pv[8];
          #pragma unroll
          for (int q = 0; q < 8; ++q) pv[q] = *(const float4*)&pan[j][4*q];
          const float rpiv = 1.0f / pan[j][j];
          __builtin_amdgcn_wave_barrier();
          // rank-1 update, lane-per-row, float4 LDS ops
          for (int r = j + 1 + lane; r < rows; r += 64){
            float f = pan[r][j] * rpiv;
            pan[r][j] = f;
            #pragma unroll
            for (int q = 0; q < 8; ++q){
              if (4*q + 3 > j){        // quad has at least one col > j (uniform)
                float4 av = *(float4*)&pan[r][4*q];
                float4 nv;
                nv.x = (4*q+0 > j) ? fmaf(-f, pv[q].x, av.x) : av.x;
                nv.y = (4*q+1 > j) ? fmaf(-f, pv[q].y, av.y) : av.y;
                nv.z = (4*q+2 > j) ? fmaf(-f, pv[q].z, av.z) : av.z;
                nv.w = (4*q+3 > j) ? fmaf(-f, pv[q].w, av.w) : av.w;
                *(float4*)&pan[r][4*q] = nv;
              }
            }
          }
          __builtin_amdgcn_wave_barrier();
          __builtin_amdgcn_sched_barrier(0);
        }
      } else {                         // tail panel: nb == 3, rows == 3
        for (int j = 0; j < 3; ++j){
          float bv = -1.0f; int bi = j;
          for (int i = j + lane; i < rows; i += 64){
            float a = fabsf(pan[i][j]);
            if (a > bv){ bv = a; bi = i; }
          }
          #pragma unroll
          for (int off = 32; off; off >>= 1){
            float ov = __shfl_xor(bv, off);
            int   oi = __shfl_xor(bi, off);
            if (ov > bv || (ov == bv && oi < bi)){ bv = ov; bi = oi; }
          }
          if (lane == 0) pivloc[j] = bi;
          if (bi != j && lane < 3){
            float t = pan[j][lane]; pan[j][lane] = pan[bi][lane]; pan[bi][lane] = t;
          }
          __builtin_amdgcn_wave_barrier();
          __builtin_amdgcn_sched_barrier(0);
          const float rpiv = 1.0f / pan[j][j];
          for (int r = j + 1 + lane; r < rows; r += 64){
            float f = pan[r][j] * rpiv;
            pan[r][j] = f;
            for (int c = j + 1; c < 3; ++c)
              pan[r][c] = fmaf(-f, pan[j][c], pan[r][c]);
          }
          __builtin_amdgcn_wave_barrier();
          __builtin_amdgcn_sched_barrier(0);
        }
      }
    }
    __syncthreads();

    // ---- write back U11/L11 block (rows 0..nb-1, panel cols) ----
    for (int idx = tid; idx < nb*nb; idx += 512){
      int r = idx / nb, c = idx - r*nb;
      Ab[(size_t)(k0+r)*APITCH + k0 + c] = pan[r][c];
    }
    // ---- compose row permutation of this panel ----
    for (int i = tid; i < rows; i += 512) perm[i] = i;
    __syncthreads();
    if (tid == 0){
      for (int j = 0; j < nb; ++j){
        int pj = pivloc[j];
        int t = perm[j]; perm[j] = perm[pj]; perm[pj] = t;
      }
    }
    __syncthreads();
    for (int i = tid; i < rows; i += 512)
      if (perm[i] != i){ int s = atomicAdd(&mvcnt, 1); mvlist[s] = i; }
    __syncthreads();

    // ---- laswp: permute trailing cols of moved rows (gather via LDS) ----
    const int M = mvcnt;               // <= 64
    if (tc > 0 && M > 0){
      for (int idx = tid; idx < M*tc; idx += 512){
        int m = idx / tc, c = idx - m*tc;
        stg[m][c] = Ab[(size_t)(k0 + perm[mvlist[m]])*APITCH + ctop + c];
      }
      __syncthreads();
      for (int idx = tid; idx < M*tc; idx += 512){
        int m = idx / tc, c = idx - m*tc;
        Ab[(size_t)(k0 + mvlist[m])*APITCH + ctop + c] = stg[m][c];
      }
      __syncthreads();
    }

    // ---- TRSM: U12 = L11^{-1} A12 (incl rhs cols), thread-per-column ----
    if (tc > 0){
      if (nb == NB){
        for (int c = tid; c < tc; c += 512){
          float u[NB];
          #pragma unroll
          for (int m = 0; m < NB; ++m) u[m] = Ab[(size_t)(k0+m)*APITCH + ctop + c];
          #pragma unroll
          for (int m = 0; m < NB; ++m){
            #pragma unroll
            for (int jj = m+1; jj < NB; ++jj)
              u[jj] = fmaf(-pan[jj][m], u[m], u[jj]);
          }
          #pragma unroll
          for (int m = 0; m < NB; ++m){
            Ab[(size_t)(k0+m)*APITCH + ctop + c] = u[m];
            stg[m][c] = u[m];
          }
        }
      } else {                         // nb == 3 tail panel
        for (int c = tid; c < tc; c += 512){
          float u0 = Ab[(size_t)(k0+0)*APITCH + ctop + c];
          float u1 = Ab[(size_t)(k0+1)*APITCH + ctop + c];
          float u2 = Ab[(size_t)(k0+2)*APITCH + ctop + c];
          u1 = fmaf(-pan[1][0], u0, u1);
          u2 = fmaf(-pan[2][0], u0, u2);
          u2 = fmaf(-pan[2][1], u1, u2);
          Ab[(size_t)(k0+0)*APITCH + ctop + c] = u0;
          Ab[(size_t)(k0+1)*APITCH + ctop + c] = u1;
          Ab[(size_t)(k0+2)*APITCH + ctop + c] = u2;
        }
      }
      __syncthreads();
    }

    // ---- GEMM: A22 -= L21 * U12, 4x4 register tiles, float4 LDS reads ----
    const int R = rows - nb;
    if (R > 0 && tc > 0){
      const int rt = (R + 3) >> 2, ct = (tc + 3) >> 2;
      for (int t = tid; t < rt*ct; t += 512){
        int tr = t / ct, tcc = t - tr*ct;
        int i0 = nb + tr*4, c0 = tcc*4;
        const bool full = (c0 + 4 <= tc);
        int ir[4];
        #pragma unroll
        for (int r = 0; r < 4; ++r){
          int i = i0 + r;
          ir[r] = (i < rows) ? i : (rows - 1);
        }
        float acc[4][4];
        #pragma unroll
        for (int r = 0; r < 4; ++r){
          const float* g = Ab + (size_t)(k0+ir[r])*APITCH + ctop + c0;
          bool rowok = (i0 + r < rows);
          if (rowok && full){
            float4 v = *(const float4*)g;
            acc[r][0]=v.x; acc[r][1]=v.y; acc[r][2]=v.z; acc[r][3]=v.w;
          } else {
            #pragma unroll
            for (int c = 0; c < 4; ++c)
              acc[r][c] = (rowok && (c0 + c < tc)) ? g[c] : 0.0f;
          }
        }
        #pragma unroll
        for (int mq = 0; mq < NB/4; ++mq){
          float4 lv[4];
          #pragma unroll
          for (int r = 0; r < 4; ++r)
            lv[r] = *(const float4*)&pan[ir[r]][4*mq];
          #pragma unroll
          for (int mi = 0; mi < 4; ++mi){
            float4 uv = *(const float4*)&stg[4*mq + mi][c0];
            #pragma unroll
            for (int r = 0; r < 4; ++r){
              float l = (mi==0) ? lv[r].x : (mi==1) ? lv[r].y : (mi==2) ? lv[r].z : lv[r].w;
              acc[r][0] = fmaf(-l, uv.x, acc[r][0]);
              acc[r][1] = fmaf(-l, uv.y, acc[r][1]);
              acc[r][2] = fmaf(-l, uv.z, acc[r][2]);
              acc[r][3] = fmaf(-l, uv.w, acc[r][3]);
            }
          }
        }
        #pragma unroll
        for (int r = 0; r < 4; ++r){
          if (i0 + r < rows){
            float* g = Ab + (size_t)(k0+ir[r])*APITCH + ctop + c0;
            if (full){
              float4 v; v.x=acc[r][0]; v.y=acc[r][1]; v.z=acc[r][2]; v.w=acc[r][3];
              *(float4*)g = v;
            } else {
              #pragma unroll
              for (int c = 0; c < 4; ++c)
                if (c0 + c < tc) g[c] = acc[r][c];
            }
          }
        }
      }
      __syncthreads();
    }
  }

  // ======================== blocked back-substitution ========================
  for (int bp = NPAN-1; bp >= 0; --bp){
    const int k0 = bp*NB;
    const int nb = (NA - k0 < NB) ? (NA - k0) : NB;
    const int cs = k0 + nb;
    const int below = NA - cs;

    {
      int g = tid >> 3, sub = tid & 7;
      int row = g >> 1, ch = g & 1;
      float s = 0.0f;
      if (row < nb){
        const size_t rbase = (size_t)(k0+row)*APITCH;
        if (sub == 0) s = Ab[rbase + NA + ch];
        for (int c = sub; c < below; c += 8)
          s -= Ab[rbase + cs + c] * xs2[(cs + c)*2 + ch];
      }
      s += __shfl_xor(s, 4); s += __shfl_xor(s, 2); s += __shfl_xor(s, 1);
      if (row < nb && sub == 0) tsum[row][ch] = s;
    }
    for (int idx = tid; idx < nb*nb; idx += 512){
      int r = idx / nb, c = idx - r*nb;
      pan[r][c] = Ab[(size_t)(k0+r)*APITCH + k0 + c];
    }
    __syncthreads();
    if (wid == 0){
      int j = lane >> 1, ch = lane & 1;
      float tval = (j < nb) ? tsum[j][ch] : 0.0f;
      for (int k = nb-1; k >= 0; --k){
        float tk = __shfl(tval, 2*k + ch);
        float xk = tk / pan[k][k];
        if (j <  k) tval = fmaf(-pan[j][k], xk, tval);
        if (j == k) tval = xk;
      }
      if (j < nb) xs2[(k0+j)*2 + ch] = tval;
    }
    __syncthreads();
  }

  for (int i = tid; i < NA; i += 512){
    wv[((size_t)b*NA + i)*2 + 0] = xs2[i*2+0];
    wv[((size_t)b*NA + i)*2 + 1] = xs2[i*2+1];
  }
}

// ---------------------------------------------------------------------------
// Kernel 3: evaluate the warp on the s x s grid (float2 LDS reads).
// ---------------------------------------------------------------------------
__global__ __launch_bounds__(256) void eval_kernel(const float* __restrict__ src,
                                                   const float* __restrict__ wv,
                                                   float* __restrict__ out){
  const int b  = blockIdx.x >> 8;
  const int yi = blockIdx.x & 255;
  const int xi = threadIdx.x;
  __shared__ float2 sxy[NCTRL], wxy[NCTRL];
  const float* sb = src + b*NCTRL*2;
  const float* wb = wv + (size_t)b*NA*2;
  sxy[xi] = ((const float2*)sb)[xi];
  wxy[xi] = ((const float2*)wb)[xi];
  __syncthreads();

  const float step = 2.0f/255.0f;
  const float gx = -1.0f + step*(float)xi;
  const float gy = -1.0f + step*(float)yi;

  float accx = wb[512] + wb[514]*gx + wb[516]*gy;
  float accy = wb[513] + wb[515]*gx + wb[517]*gy;

  #pragma unroll 8
  for (int j = 0; j < NCTRL; ++j){
    float2 s = sxy[j];
    float2 w = wxy[j];
    float dx = gx - s.x;
    float dy = gy - s.y;
    float r = sqrtf(fmaf(dx, dx, dy*dy));
    accx = fmaf(r, w.x, accx);
    accy = fmaf(r, w.y, accy);
  }
  out[((size_t)(b*2    )*SGRID + yi)*SGRID + xi] = accx;
  out[((size_t)(b*2 + 1)*SGRID + yi)*SGRID + xi] = accy;
}

// ---------------------------------------------------------------------------
extern "C" void kernel_launch(void* const* d_in, const int* in_sizes, int n_in,
                              void* d_out, int out_size, void* d_ws, size_t ws_size,
                              hipStream_t stream) {
  const float* src = (const float*)d_in[0];
  const float* dst = (const float*)d_in[1];
  float* out = (float*)d_out;

  const size_t matElems = (size_t)BATCH*NA*APITCH;
  float* A  = (float*)d_ws;
  float* wv = A + matElems;

  build_kernel<<<BATCH, 256, 0, stream>>>(src, dst, A);
  lu_blocked<<<BATCH, 512, 0, stream>>>(A, wv);
  eval_kernel<<<BATCH*SGRID, 256, 0, stream>>>(src, wv, out);
}

// Round 6
// 650.246 us; speedup vs baseline: 3.8873x; 1.5870x over previous
//
#include <hip/hip_runtime.h>
#include <math.h>

// Problem constants (fixed by setup_inputs: B=8, n=256, s=256)
#define NCTRL 256          // control points
#define NA    259          // n + 3 (TPS system size)
#define NAUG  261          // + 2 rhs columns
#define APITCH 264         // padded row pitch (floats) for the augmented matrix
#define BATCH 8
#define SGRID 256
#define NB    32           // LU panel width
#define NPAN  9            // 8 full panels + 1 of width 3
#define PPITCH 36          // LDS row pitch: 36*4=144B, 16B-aligned rows

// ---------------------------------------------------------------------------
// Kernel 1: build the augmented TPS system. 13 row-strips per batch.
// ---------------------------------------------------------------------------
__global__ __launch_bounds__(256) void build_kernel(const float* __restrict__ src,
                                                    const float* __restrict__ dst,
                                                    float* __restrict__ A){
  const int b = blockIdx.x / 13;
  const int s = blockIdx.x - b*13;
  const int r0 = s*20;
  const int r1 = (r0 + 20 < NA) ? r0 + 20 : NA;
  const float* sb = src + b*NCTRL*2;
  const float* db = dst + b*NCTRL*2;
  float* Ab = A + (size_t)b*NA*APITCH;
  __shared__ float sx[NCTRL], sy[NCTRL];
  {
    int t = threadIdx.x;
    float2 v = ((const float2*)sb)[t];
    sx[t] = v.x; sy[t] = v.y;
  }
  __syncthreads();
  const int total = (r1 - r0)*APITCH;
  for (int idx = threadIdx.x; idx < total; idx += 256){
    int r = r0 + idx / APITCH;
    int c = idx % APITCH;
    float v = 0.0f;
    if (r < NCTRL){
      if (c < NCTRL){
        float dx = sx[r] - sx[c];
        float dy = sy[r] - sy[c];
        v = sqrtf(fmaf(dx, dx, dy*dy));
      } else if (c == NCTRL)   v = 1.0f;
      else if (c == NCTRL+1)   v = sx[r];
      else if (c == NCTRL+2)   v = sy[r];
      else if (c == NA)        v = db[2*r];
      else if (c == NA+1)      v = db[2*r+1];
    } else if (c < NCTRL){
      v = (r == NCTRL) ? 1.0f : ((r == NCTRL+1) ? sx[c] : sy[c]);
    }
    Ab[(size_t)r*APITCH + c] = v;
  }
}

// ---------------------------------------------------------------------------
// Kernel 2a: panel factorization, 1 block/batch, 320 threads (5 waves),
// thread-per-row with the row in 32 VGPRs. ONE barrier per ministep:
// each wave's argmax winner publishes (val,idx,org,row) BEFORE the barrier
// (parity double-buffered), everyone scans 5 candidates after it.
// Origin tracking (org) yields the row permutation for free.
// ---------------------------------------------------------------------------
template<int NBC>
__global__ __launch_bounds__(320) void panel_kernel(float* __restrict__ A,
                                                    int* __restrict__ permbuf,
                                                    int k0, int pidx){
  const int b = blockIdx.x;
  float* Ab = A + (size_t)b*NA*APITCH;
  const int tid  = threadIdx.x;
  const int lane = tid & 63;
  const int wid  = tid >> 6;          // 0..4
  const int rows = NA - k0;

  __shared__ float pan[NA][PPITCH];        // 37.3 KB staging
  __shared__ float redrow[2][5][PPITCH];   // per-wave winner rows (parity dbuf)
  __shared__ float jrow[2][PPITCH];        // displaced row j
  __shared__ float redv[2][5];
  __shared__ int   redi[2][5], redo[2][5];
  __shared__ int   jorg[2];

  // ---- stage panel coalesced (global -> LDS) ----
  if (NBC == NB){
    for (int idx = tid; idx < rows*8; idx += 320){
      int i = idx >> 3, q = idx & 7;
      *(float4*)&pan[i][4*q] =
        *(const float4*)(Ab + (size_t)(k0+i)*APITCH + k0 + 4*q);
    }
  } else {
    for (int idx = tid; idx < rows*NBC; idx += 320){
      int i = idx / NBC, c = idx - i*NBC;
      pan[i][c] = Ab[(size_t)(k0+i)*APITCH + k0 + c];
    }
  }
  __syncthreads();

  // ---- my row -> registers ----
  float rr[NBC];
  int org = tid;
  if (tid < rows){
    if (NBC == NB){
      #pragma unroll
      for (int q = 0; q < 8; ++q){
        float4 v = *(const float4*)&pan[tid][4*q];
        rr[4*q]=v.x; rr[4*q+1]=v.y; rr[4*q+2]=v.z; rr[4*q+3]=v.w;
      }
    } else {
      #pragma unroll
      for (int c = 0; c < NBC; ++c) rr[c] = pan[tid][c];
    }
  } else {
    #pragma unroll
    for (int c = 0; c < NBC; ++c) rr[c] = 0.0f;
  }

  // ---- ministeps: 1 barrier each ----
  #pragma unroll
  for (int j = 0; j < NBC; ++j){
    const int par = j & 1;
    // in-wave argmax over this wave's rows
    float bv = (tid >= j && tid < rows) ? fabsf(rr[j]) : -1.0f;
    int bi = tid;
    #pragma unroll
    for (int off = 32; off; off >>= 1){
      float ov = __shfl_xor(bv, off);
      int   oi = __shfl_xor(bi, off);
      if (ov > bv || (ov == bv && oi < bi)){ bv = ov; bi = oi; }
    }
    // per-wave winner publishes value/idx/org + its row
    if (tid == bi){
      redv[par][wid] = bv; redi[par][wid] = bi; redo[par][wid] = org;
      if (bv >= 0.0f){
        if (NBC == NB){
          #pragma unroll
          for (int q = 0; q < 8; ++q){
            float4 v; v.x=rr[4*q]; v.y=rr[4*q+1]; v.z=rr[4*q+2]; v.w=rr[4*q+3];
            *(float4*)&redrow[par][wid][4*q] = v;
          }
        } else {
          #pragma unroll
          for (int c = 0; c < NBC; ++c) redrow[par][wid][c] = rr[c];
        }
      }
    }
    // row j publishes itself (for the swap)
    if (tid == j){
      jorg[par] = org;
      if (NBC == NB){
        #pragma unroll
        for (int q = 0; q < 8; ++q){
          float4 v; v.x=rr[4*q]; v.y=rr[4*q+1]; v.z=rr[4*q+2]; v.w=rr[4*q+3];
          *(float4*)&jrow[par][4*q] = v;
        }
      } else {
        #pragma unroll
        for (int c = 0; c < NBC; ++c) jrow[par][c] = rr[c];
      }
    }
    __syncthreads();
    // global winner among 5 wave candidates
    float gv = redv[par][0]; int gw = 0;
    #pragma unroll
    for (int w = 1; w < 5; ++w){
      if (redv[par][w] > gv ||
          (redv[par][w] == gv && redi[par][w] < redi[par][gw])){
        gv = redv[par][w]; gw = w;
      }
    }
    const int gbi  = redi[par][gw];
    const int gorg = redo[par][gw];
    // pivot row -> registers (broadcast reads)
    float pr[NBC];
    if (NBC == NB){
      #pragma unroll
      for (int q = 0; q < 8; ++q){
        float4 v = *(const float4*)&redrow[par][gw][4*q];
        pr[4*q]=v.x; pr[4*q+1]=v.y; pr[4*q+2]=v.z; pr[4*q+3]=v.w;
      }
    } else {
      #pragma unroll
      for (int c = 0; c < NBC; ++c) pr[c] = redrow[par][gw][c];
    }
    // swap rows j <-> gbi (register adopt)
    if (gbi != j){
      if (tid == j){
        #pragma unroll
        for (int c = 0; c < NBC; ++c) rr[c] = pr[c];
        org = gorg;
      } else if (tid == gbi){
        #pragma unroll
        for (int c = 0; c < NBC; ++c) rr[c] = jrow[par][c];
        org = jorg[par];
      }
    }
    // rank-1 update in registers
    if (tid > j && tid < rows){
      const float rpiv = 1.0f / pr[j];
      float f = rr[j] * rpiv;
      rr[j] = f;
      #pragma unroll
      for (int c = j+1; c < NBC; ++c) rr[c] = fmaf(-f, pr[c], rr[c]);
    }
  }

  // ---- write back: regs -> LDS -> global (coalesced); perm out ----
  if (tid < rows){
    if (NBC == NB){
      #pragma unroll
      for (int q = 0; q < 8; ++q){
        float4 v; v.x=rr[4*q]; v.y=rr[4*q+1]; v.z=rr[4*q+2]; v.w=rr[4*q+3];
        *(float4*)&pan[tid][4*q] = v;
      }
    } else {
      #pragma unroll
      for (int c = 0; c < NBC; ++c) pan[tid][c] = rr[c];
    }
    permbuf[b*(NPAN*NA) + pidx*NA + tid] = org;
  }
  __syncthreads();
  if (NBC == NB){
    for (int idx = tid; idx < rows*8; idx += 320){
      int i = idx >> 3, q = idx & 7;
      *(float4*)(Ab + (size_t)(k0+i)*APITCH + k0 + 4*q) = *(const float4*)&pan[i][4*q];
    }
  } else {
    for (int idx = tid; idx < rows*NBC; idx += 320){
      int i = idx / NBC, c = idx - i*NBC;
      Ab[(size_t)(k0+i)*APITCH + k0 + c] = pan[i][c];
    }
  }
}

// ---------------------------------------------------------------------------
// Kernel 2b: trailing update for one panel, one block per 32-col strip.
// laswp(gather into LDS) + TRSM(LDS) + GEMM(LDS-sourced) fused; one global
// read pass + one global write pass of the strip.
// ---------------------------------------------------------------------------
template<int NBC>
__global__ __launch_bounds__(256) void update_kernel(float* __restrict__ A,
                                                     const int* __restrict__ permbuf,
                                                     int k0, int pidx, int sb){
  const int rows = NA - k0;
  const int ctop = k0 + NBC;
  const int tc   = NAUG - ctop;
  const int b    = blockIdx.x / sb;
  const int s    = blockIdx.x - b*sb;
  const int c0   = s*32;
  const int W    = (tc - c0 < 32) ? (tc - c0) : 32;
  float* Ab = A + (size_t)b*NA*APITCH;
  const int tid = threadIdx.x;

  __shared__ float pan[NA][PPITCH];     // factored panel (L\U)
  __shared__ float stage[NA][PPITCH];   // permuted strip
  __shared__ float ustg[NB][PPITCH];    // U12 strip
  __shared__ int   perm[NA];

  for (int i = tid; i < rows; i += 256)
    perm[i] = permbuf[b*(NPAN*NA) + pidx*NA + i];
  if (NBC == NB){
    for (int idx = tid; idx < rows*8; idx += 256){
      int i = idx >> 3, q = idx & 7;
      *(float4*)&pan[i][4*q] =
        *(const float4*)(Ab + (size_t)(k0+i)*APITCH + k0 + 4*q);
    }
  } else {
    for (int idx = tid; idx < rows*NBC; idx += 256){
      int i = idx / NBC, c = idx - i*NBC;
      pan[i][c] = Ab[(size_t)(k0+i)*APITCH + k0 + c];
    }
  }
  __syncthreads();

  // ---- laswp gather: stage[i][c] = A[k0+perm[i]][ctop+c0+c] ----
  for (int idx = tid; idx < rows*W; idx += 256){
    int i = idx / W, c = idx - i*W;
    stage[i][c] = Ab[(size_t)(k0+perm[i])*APITCH + ctop + c0 + c];
  }
  __syncthreads();

  // ---- TRSM: U12 = L11^{-1} A12, thread-per-column from LDS ----
  if (tid < W){
    float u[NBC];
    #pragma unroll
    for (int m = 0; m < NBC; ++m) u[m] = stage[m][tid];
    #pragma unroll
    for (int m = 0; m < NBC; ++m){
      #pragma unroll
      for (int jj = m+1; jj < NBC; ++jj)
        u[jj] = fmaf(-pan[jj][m], u[m], u[jj]);
    }
    #pragma unroll
    for (int m = 0; m < NBC; ++m){
      ustg[m][tid] = u[m];
      Ab[(size_t)(k0+m)*APITCH + ctop + c0 + tid] = u[m];
    }
  }
  __syncthreads();

  // ---- GEMM: A22 -= L21 * U12 (acc init from stage, write global) ----
  const int R = rows - NBC;
  if (R > 0){
    const int rt = (R + 3) >> 2, ct = (W + 3) >> 2;
    for (int t = tid; t < rt*ct; t += 256){
      int tr = t / ct, tcc = t - tr*ct;
      int i0 = tr*4, cc0 = tcc*4;
      const bool full = (cc0 + 4 <= W);
      int ir[4];
      #pragma unroll
      for (int r = 0; r < 4; ++r){
        int i = i0 + r;
        ir[r] = (i < R) ? i : (R - 1);
      }
      float acc[4][4];
      #pragma unroll
      for (int r = 0; r < 4; ++r){
        if (full){
          float4 v = *(const float4*)&stage[NBC + ir[r]][cc0];
          acc[r][0]=v.x; acc[r][1]=v.y; acc[r][2]=v.z; acc[r][3]=v.w;
        } else {
          #pragma unroll
          for (int c = 0; c < 4; ++c)
            acc[r][c] = (cc0 + c < W) ? stage[NBC + ir[r]][cc0 + c] : 0.0f;
        }
      }
      #pragma unroll
      for (int mq = 0; mq < NBC/4; ++mq){
        float4 lv[4];
        #pragma unroll
        for (int r = 0; r < 4; ++r)
          lv[r] = *(const float4*)&pan[NBC + ir[r]][4*mq];
        #pragma unroll
        for (int mi = 0; mi < 4; ++mi){
          float4 uv = *(const float4*)&ustg[4*mq + mi][cc0];
          #pragma unroll
          for (int r = 0; r < 4; ++r){
            float l = (mi==0) ? lv[r].x : (mi==1) ? lv[r].y : (mi==2) ? lv[r].z : lv[r].w;
            acc[r][0] = fmaf(-l, uv.x, acc[r][0]);
            acc[r][1] = fmaf(-l, uv.y, acc[r][1]);
            acc[r][2] = fmaf(-l, uv.z, acc[r][2]);
            acc[r][3] = fmaf(-l, uv.w, acc[r][3]);
          }
        }
      }
      // tail NBC%4 (NBC==3 path)
      if (NBC & 3){
        #pragma unroll
        for (int mi = NBC & ~3; mi < NBC; ++mi){
          #pragma unroll
          for (int r = 0; r < 4; ++r){
            float l = pan[NBC + ir[r]][mi];
            #pragma unroll
            for (int c = 0; c < 4; ++c)
              acc[r][c] = fmaf(-l, ustg[mi][cc0 + c], acc[r][c]);
          }
        }
      }
      #pragma unroll
      for (int r = 0; r < 4; ++r){
        if (i0 + r < R){
          float* g = Ab + (size_t)(k0 + NBC + i0 + r)*APITCH + ctop + c0 + cc0;
          if (full){
            float4 v; v.x=acc[r][0]; v.y=acc[r][1]; v.z=acc[r][2]; v.w=acc[r][3];
            *(float4*)g = v;
          } else {
            #pragma unroll
            for (int c = 0; c < 4; ++c)
              if (cc0 + c < W) g[c] = acc[r][c];
          }
        }
      }
    }
  }
}

// ---------------------------------------------------------------------------
// Kernel 2c: blocked back-substitution, one block/batch (from r2, standalone).
// ---------------------------------------------------------------------------
__global__ __launch_bounds__(512) void backsub_kernel(const float* __restrict__ A,
                                                      float* __restrict__ wv){
  const int b = blockIdx.x;
  const float* Ab = A + (size_t)b*NA*APITCH;
  const int tid  = threadIdx.x;
  const int lane = tid & 63;
  const int wid  = tid >> 6;

  __shared__ float u11[NB][NB+1];
  __shared__ float xs2[2*NA];
  __shared__ float tsum[NB][2];

  for (int bp = NPAN-1; bp >= 0; --bp){
    const int k0 = bp*NB;
    const int nb = (NA - k0 < NB) ? (NA - k0) : NB;
    const int cs = k0 + nb;
    const int below = NA - cs;

    {
      int g = tid >> 3, sub = tid & 7;
      int row = g >> 1, ch = g & 1;
      float s = 0.0f;
      if (row < nb){
        const size_t rbase = (size_t)(k0+row)*APITCH;
        if (sub == 0) s = Ab[rbase + NA + ch];
        for (int c = sub; c < below; c += 8)
          s -= Ab[rbase + cs + c] * xs2[(cs + c)*2 + ch];
      }
      s += __shfl_xor(s, 4); s += __shfl_xor(s, 2); s += __shfl_xor(s, 1);
      if (row < nb && sub == 0) tsum[row][ch] = s;
    }
    for (int idx = tid; idx < nb*nb; idx += 512){
      int r = idx / nb, c = idx - r*nb;
      u11[r][c] = Ab[(size_t)(k0+r)*APITCH + k0 + c];
    }
    __syncthreads();
    if (wid == 0){
      int j = lane >> 1, ch = lane & 1;
      float tval = (j < nb) ? tsum[j][ch] : 0.0f;
      for (int k = nb-1; k >= 0; --k){
        float tk = __shfl(tval, 2*k + ch);
        float xk = tk / u11[k][k];
        if (j <  k) tval = fmaf(-u11[j][k], xk, tval);
        if (j == k) tval = xk;
      }
      if (j < nb) xs2[(k0+j)*2 + ch] = tval;
    }
    __syncthreads();
  }

  for (int i = tid; i < NA; i += 512){
    wv[((size_t)b*NA + i)*2 + 0] = xs2[i*2+0];
    wv[((size_t)b*NA + i)*2 + 1] = xs2[i*2+1];
  }
}

// ---------------------------------------------------------------------------
// Kernel 3: evaluate the warp on the s x s grid.
// ---------------------------------------------------------------------------
__global__ __launch_bounds__(256) void eval_kernel(const float* __restrict__ src,
                                                   const float* __restrict__ wv,
                                                   float* __restrict__ out){
  const int b  = blockIdx.x >> 8;
  const int yi = blockIdx.x & 255;
  const int xi = threadIdx.x;
  __shared__ float2 sxy[NCTRL], wxy[NCTRL];
  const float* sb = src + b*NCTRL*2;
  const float* wb = wv + (size_t)b*NA*2;
  sxy[xi] = ((const float2*)sb)[xi];
  wxy[xi] = ((const float2*)wb)[xi];
  __syncthreads();

  const float step = 2.0f/255.0f;
  const float gx = -1.0f + step*(float)xi;
  const float gy = -1.0f + step*(float)yi;

  float accx = wb[512] + wb[514]*gx + wb[516]*gy;
  float accy = wb[513] + wb[515]*gx + wb[517]*gy;

  #pragma unroll 8
  for (int j = 0; j < NCTRL; ++j){
    float2 s = sxy[j];
    float2 w = wxy[j];
    float dx = gx - s.x;
    float dy = gy - s.y;
    float r = sqrtf(fmaf(dx, dx, dy*dy));
    accx = fmaf(r, w.x, accx);
    accy = fmaf(r, w.y, accy);
  }
  out[((size_t)(b*2    )*SGRID + yi)*SGRID + xi] = accx;
  out[((size_t)(b*2 + 1)*SGRID + yi)*SGRID + xi] = accy;
}

// ---------------------------------------------------------------------------
extern "C" void kernel_launch(void* const* d_in, const int* in_sizes, int n_in,
                              void* d_out, int out_size, void* d_ws, size_t ws_size,
                              hipStream_t stream) {
  const float* src = (const float*)d_in[0];
  const float* dst = (const float*)d_in[1];
  float* out = (float*)d_out;

  const size_t matElems = (size_t)BATCH*NA*APITCH;
  float* A     = (float*)d_ws;
  float* wv    = A + matElems;
  int*   permb = (int*)(wv + (size_t)BATCH*NA*2);

  build_kernel<<<BATCH*13, 256, 0, stream>>>(src, dst, A);

  for (int p = 0; p < NPAN; ++p){
    const int k0 = p*NB;
    if (p < NPAN-1){
      panel_kernel<NB><<<BATCH, 320, 0, stream>>>(A, permb, k0, p);
      const int tc = NAUG - (k0 + NB);
      const int sb = (tc + 31) >> 5;
      update_kernel<NB><<<BATCH*sb, 256, 0, stream>>>(A, permb, k0, p, sb);
    } else {
      panel_kernel<3><<<BATCH, 320, 0, stream>>>(A, permb, k0, p);
      update_kernel<3><<<BATCH, 256, 0, stream>>>(A, permb, k0, p, 1);
    }
  }

  backsub_kernel<<<BATCH, 512, 0, stream>>>(A, wv);
  eval_kernel<<<BATCH*SGRID, 256, 0, stream>>>(src, wv, out);
}

// Round 7
// 595.396 us; speedup vs baseline: 4.2454x; 1.0921x over previous
//
#include <hip/hip_runtime.h>
#include <math.h>

// Problem constants (fixed by setup_inputs: B=8, n=256, s=256)
#define NCTRL 256          // control points
#define NA    259          // n + 3 (TPS system size)
#define NAUG  261          // + 2 rhs columns
#define APITCH 264         // padded row pitch (floats) for the augmented matrix
#define BATCH 8
#define SGRID 256
#define NB    32           // LU panel width
#define NPAN  9            // 8 full panels + 1 of width 3
#define PPITCH 36          // LDS row pitch: 36*4=144B, 16B-aligned rows

// ---------------------------------------------------------------------------
// Kernel 1: build the augmented TPS system. 13 row-strips per batch.
// ---------------------------------------------------------------------------
__global__ __launch_bounds__(256) void build_kernel(const float* __restrict__ src,
                                                    const float* __restrict__ dst,
                                                    float* __restrict__ A){
  const int b = blockIdx.x / 13;
  const int s = blockIdx.x - b*13;
  const int r0 = s*20;
  const int r1 = (r0 + 20 < NA) ? r0 + 20 : NA;
  const float* sb = src + b*NCTRL*2;
  const float* db = dst + b*NCTRL*2;
  float* Ab = A + (size_t)b*NA*APITCH;
  __shared__ float sx[NCTRL], sy[NCTRL];
  {
    int t = threadIdx.x;
    float2 v = ((const float2*)sb)[t];
    sx[t] = v.x; sy[t] = v.y;
  }
  __syncthreads();
  const int total = (r1 - r0)*APITCH;
  for (int idx = threadIdx.x; idx < total; idx += 256){
    int r = r0 + idx / APITCH;
    int c = idx % APITCH;
    float v = 0.0f;
    if (r < NCTRL){
      if (c < NCTRL){
        float dx = sx[r] - sx[c];
        float dy = sy[r] - sy[c];
        v = sqrtf(fmaf(dx, dx, dy*dy));
      } else if (c == NCTRL)   v = 1.0f;
      else if (c == NCTRL+1)   v = sx[r];
      else if (c == NCTRL+2)   v = sy[r];
      else if (c == NA)        v = db[2*r];
      else if (c == NA+1)      v = db[2*r+1];
    } else if (c < NCTRL){
      v = (r == NCTRL) ? 1.0f : ((r == NCTRL+1) ? sx[c] : sy[c]);
    }
    Ab[(size_t)r*APITCH + c] = v;
  }
}

// ---------------------------------------------------------------------------
// Shared ministep engine (extracted verbatim from the r6-proven panel code).
// Thread tid owns row tid of the panel in rr[] (registers). One barrier per
// ministep; parity double-buffered publish. NW = number of waves in block.
// ---------------------------------------------------------------------------
template<int NBC, int NW>
__device__ __forceinline__ void panel_ministeps(
    float (&rr)[NBC], int& org, const int rows,
    const int tid, const int lane, const int wid,
    float (*redrow)[NW][PPITCH], float (*jrow)[PPITCH],
    float (*redv)[NW], int (*redi)[NW], int (*redo_)[NW], int* jorg)
{
  #pragma unroll
  for (int j = 0; j < NBC; ++j){
    const int par = j & 1;
    // in-wave argmax over this wave's rows
    float bv = (tid >= j && tid < rows) ? fabsf(rr[j]) : -1.0f;
    int bi = tid;
    #pragma unroll
    for (int off = 32; off; off >>= 1){
      float ov = __shfl_xor(bv, off);
      int   oi = __shfl_xor(bi, off);
      if (ov > bv || (ov == bv && oi < bi)){ bv = ov; bi = oi; }
    }
    // per-wave winner publishes value/idx/org + its row
    if (tid == bi){
      redv[par][wid] = bv; redi[par][wid] = bi; redo_[par][wid] = org;
      if (bv >= 0.0f){
        if (NBC == NB){
          #pragma unroll
          for (int q = 0; q < 8; ++q){
            float4 v; v.x=rr[4*q]; v.y=rr[4*q+1]; v.z=rr[4*q+2]; v.w=rr[4*q+3];
            *(float4*)&redrow[par][wid][4*q] = v;
          }
        } else {
          #pragma unroll
          for (int c = 0; c < NBC; ++c) redrow[par][wid][c] = rr[c];
        }
      }
    }
    // row j publishes itself (for the swap)
    if (tid == j){
      jorg[par] = org;
      if (NBC == NB){
        #pragma unroll
        for (int q = 0; q < 8; ++q){
          float4 v; v.x=rr[4*q]; v.y=rr[4*q+1]; v.z=rr[4*q+2]; v.w=rr[4*q+3];
          *(float4*)&jrow[par][4*q] = v;
        }
      } else {
        #pragma unroll
        for (int c = 0; c < NBC; ++c) jrow[par][c] = rr[c];
      }
    }
    __syncthreads();
    // global winner among NW wave candidates
    float gv = redv[par][0]; int gw = 0;
    #pragma unroll
    for (int w = 1; w < NW; ++w){
      if (redv[par][w] > gv ||
          (redv[par][w] == gv && redi[par][w] < redi[par][gw])){
        gv = redv[par][w]; gw = w;
      }
    }
    const int gbi  = redi[par][gw];
    const int gorg = redo_[par][gw];
    // pivot row -> registers (broadcast reads)
    float pr[NBC];
    if (NBC == NB){
      #pragma unroll
      for (int q = 0; q < 8; ++q){
        float4 v = *(const float4*)&redrow[par][gw][4*q];
        pr[4*q]=v.x; pr[4*q+1]=v.y; pr[4*q+2]=v.z; pr[4*q+3]=v.w;
      }
    } else {
      #pragma unroll
      for (int c = 0; c < NBC; ++c) pr[c] = redrow[par][gw][c];
    }
    // swap rows j <-> gbi (register adopt)
    if (gbi != j){
      if (tid == j){
        #pragma unroll
        for (int c = 0; c < NBC; ++c) rr[c] = pr[c];
        org = gorg;
      } else if (tid == gbi){
        #pragma unroll
        for (int c = 0; c < NBC; ++c) rr[c] = jrow[par][c];
        org = jorg[par];
      }
    }
    // rank-1 update in registers
    if (tid > j && tid < rows){
      const float rpiv = 1.0f / pr[j];
      float f = rr[j] * rpiv;
      rr[j] = f;
      #pragma unroll
      for (int c = j+1; c < NBC; ++c) rr[c] = fmaf(-f, pr[c], rr[c]);
    }
  }
}

// ---------------------------------------------------------------------------
// Kernel 2a: standalone panel factorization (only needed for p=0).
// ---------------------------------------------------------------------------
template<int NBC>
__global__ __launch_bounds__(320) void panel_kernel(float* __restrict__ A,
                                                    int* __restrict__ permbuf,
                                                    int k0, int pidx){
  const int b = blockIdx.x;
  float* Ab = A + (size_t)b*NA*APITCH;
  const int tid  = threadIdx.x;
  const int lane = tid & 63;
  const int wid  = tid >> 6;          // 0..4
  const int rows = NA - k0;

  __shared__ float pan[NA][PPITCH];
  __shared__ float redrow[2][5][PPITCH];
  __shared__ float jrow[2][PPITCH];
  __shared__ float redv[2][5];
  __shared__ int   redi[2][5], redo_[2][5];
  __shared__ int   jorg[2];

  // stage panel coalesced (global -> LDS)
  for (int idx = tid; idx < rows*8; idx += 320){
    int i = idx >> 3, q = idx & 7;
    *(float4*)&pan[i][4*q] =
      *(const float4*)(Ab + (size_t)(k0+i)*APITCH + k0 + 4*q);
  }
  __syncthreads();

  float rr[NBC];
  int org = tid;
  if (tid < rows){
    #pragma unroll
    for (int q = 0; q < 8; ++q){
      float4 v = *(const float4*)&pan[tid][4*q];
      rr[4*q]=v.x; rr[4*q+1]=v.y; rr[4*q+2]=v.z; rr[4*q+3]=v.w;
    }
  } else {
    #pragma unroll
    for (int c = 0; c < NBC; ++c) rr[c] = 0.0f;
  }

  panel_ministeps<NBC,5>(rr, org, rows, tid, lane, wid,
                         redrow, jrow, redv, redi, redo_, jorg);

  // write back: regs -> LDS -> global (coalesced); perm out
  if (tid < rows){
    #pragma unroll
    for (int q = 0; q < 8; ++q){
      float4 v; v.x=rr[4*q]; v.y=rr[4*q+1]; v.z=rr[4*q+2]; v.w=rr[4*q+3];
      *(float4*)&pan[tid][4*q] = v;
    }
    permbuf[b*(NPAN*NA) + pidx*NA + tid] = org;
  }
  __syncthreads();
  for (int idx = tid; idx < rows*8; idx += 320){
    int i = idx >> 3, q = idx & 7;
    *(float4*)(Ab + (size_t)(k0+i)*APITCH + k0 + 4*q) = *(const float4*)&pan[i][4*q];
  }
}

// ---------------------------------------------------------------------------
// Kernel 2b: trailing update for one panel, one block per 32-col strip.
// laswp(gather to LDS) + TRSM(LDS) + GEMM. Strip-0 block additionally
// factorizes the NEXT panel directly from its LDS strip (lookahead) and
// writes panel+perm to global — panels 1..8 never launch separately.
// ---------------------------------------------------------------------------
template<int NBC, int NBCN, bool LOOK>
__global__ __launch_bounds__(256) void update_kernel(float* __restrict__ A,
                                                     int* __restrict__ permbuf,
                                                     int k0, int pidx, int sb){
  const int rows = NA - k0;
  const int ctop = k0 + NBC;
  const int tc   = NAUG - ctop;
  const int b    = blockIdx.x / sb;
  const int s    = blockIdx.x - b*sb;
  const int c0   = s*32;
  const int W    = (tc - c0 < 32) ? (tc - c0) : 32;
  float* Ab = A + (size_t)b*NA*APITCH;
  const int tid  = threadIdx.x;
  const int lane = tid & 63;
  const int wid  = tid >> 6;          // 0..3

  __shared__ float pan[NA][PPITCH];     // factored panel (L\U)
  __shared__ float stage[NA][PPITCH];   // permuted strip
  __shared__ float ustg[NB][PPITCH];    // U12 strip
  __shared__ int   perm[NA];
  __shared__ float redrowL[2][4][PPITCH];
  __shared__ float jrowL[2][PPITCH];
  __shared__ float redvL[2][4];
  __shared__ int   rediL[2][4], redoL[2][4];
  __shared__ int   jorgL[2];

  for (int i = tid; i < rows; i += 256)
    perm[i] = permbuf[b*(NPAN*NA) + pidx*NA + i];
  if (NBC == NB){
    for (int idx = tid; idx < rows*8; idx += 256){
      int i = idx >> 3, q = idx & 7;
      *(float4*)&pan[i][4*q] =
        *(const float4*)(Ab + (size_t)(k0+i)*APITCH + k0 + 4*q);
    }
  } else {
    for (int idx = tid; idx < rows*NBC; idx += 256){
      int i = idx / NBC, c = idx - i*NBC;
      pan[i][c] = Ab[(size_t)(k0+i)*APITCH + k0 + c];
    }
  }
  __syncthreads();

  // ---- laswp gather: stage[i][c] = A[k0+perm[i]][ctop+c0+c] ----
  for (int idx = tid; idx < rows*W; idx += 256){
    int i = idx / W, c = idx - i*W;
    stage[i][c] = Ab[(size_t)(k0+perm[i])*APITCH + ctop + c0 + c];
  }
  __syncthreads();

  // ---- TRSM: U12 = L11^{-1} A12, thread-per-column from LDS ----
  if (tid < W){
    float u[NBC];
    #pragma unroll
    for (int m = 0; m < NBC; ++m) u[m] = stage[m][tid];
    #pragma unroll
    for (int m = 0; m < NBC; ++m){
      #pragma unroll
      for (int jj = m+1; jj < NBC; ++jj)
        u[jj] = fmaf(-pan[jj][m], u[m], u[jj]);
    }
    #pragma unroll
    for (int m = 0; m < NBC; ++m){
      ustg[m][tid] = u[m];
      Ab[(size_t)(k0+m)*APITCH + ctop + c0 + tid] = u[m];
    }
  }
  __syncthreads();

  // ---- GEMM: A22 -= L21 * U12 ----
  const int R = rows - NBC;
  if (R > 0){
    const int rt = (R + 3) >> 2, ct = (W + 3) >> 2;
    for (int t = tid; t < rt*ct; t += 256){
      int tr = t / ct, tcc = t - tr*ct;
      int i0 = tr*4, cc0 = tcc*4;
      const bool full = (cc0 + 4 <= W);
      int ir[4];
      #pragma unroll
      for (int r = 0; r < 4; ++r){
        int i = i0 + r;
        ir[r] = (i < R) ? i : (R - 1);
      }
      float acc[4][4];
      #pragma unroll
      for (int r = 0; r < 4; ++r){
        if (full){
          float4 v = *(const float4*)&stage[NBC + ir[r]][cc0];
          acc[r][0]=v.x; acc[r][1]=v.y; acc[r][2]=v.z; acc[r][3]=v.w;
        } else {
          #pragma unroll
          for (int c = 0; c < 4; ++c)
            acc[r][c] = (cc0 + c < W) ? stage[NBC + ir[r]][cc0 + c] : 0.0f;
        }
      }
      if (NBC == NB){
        #pragma unroll
        for (int mq = 0; mq < NBC/4; ++mq){
          float4 lv[4];
          #pragma unroll
          for (int r = 0; r < 4; ++r)
            lv[r] = *(const float4*)&pan[NBC + ir[r]][4*mq];
          #pragma unroll
          for (int mi = 0; mi < 4; ++mi){
            float4 uv = *(const float4*)&ustg[4*mq + mi][cc0];
            #pragma unroll
            for (int r = 0; r < 4; ++r){
              float l = (mi==0) ? lv[r].x : (mi==1) ? lv[r].y : (mi==2) ? lv[r].z : lv[r].w;
              acc[r][0] = fmaf(-l, uv.x, acc[r][0]);
              acc[r][1] = fmaf(-l, uv.y, acc[r][1]);
              acc[r][2] = fmaf(-l, uv.z, acc[r][2]);
              acc[r][3] = fmaf(-l, uv.w, acc[r][3]);
            }
          }
        }
      } else {
        #pragma unroll
        for (int mi = 0; mi < NBC; ++mi){
          #pragma unroll
          for (int r = 0; r < 4; ++r){
            float l = pan[NBC + ir[r]][mi];
            #pragma unroll
            for (int c = 0; c < 4; ++c)
              acc[r][c] = fmaf(-l, ustg[mi][cc0 + c], acc[r][c]);
          }
        }
      }
      #pragma unroll
      for (int r = 0; r < 4; ++r){
        if (i0 + r < R){
          float* g = Ab + (size_t)(k0 + NBC + i0 + r)*APITCH + ctop + c0 + cc0;
          if (full){
            float4 v; v.x=acc[r][0]; v.y=acc[r][1]; v.z=acc[r][2]; v.w=acc[r][3];
            *(float4*)g = v;
            if (LOOK && s == 0) *(float4*)&stage[NBC + i0 + r][cc0] = v;
          } else {
            #pragma unroll
            for (int c = 0; c < 4; ++c)
              if (cc0 + c < W){
                g[c] = acc[r][c];
                if (LOOK && s == 0) stage[NBC + i0 + r][cc0 + c] = acc[r][c];
              }
          }
        }
      }
    }
  }

  // ---- lookahead: factor the NEXT panel from LDS (strip 0 only) ----
  if (LOOK && s == 0){
    __syncthreads();
    const int k0n   = k0 + NBC;
    const int rowsN = rows - NBC;
    float rr[NBCN];
    int org = tid;
    if (tid < rowsN){
      #pragma unroll
      for (int c = 0; c < NBCN; ++c) rr[c] = stage[NBC + tid][c];
    } else {
      #pragma unroll
      for (int c = 0; c < NBCN; ++c) rr[c] = 0.0f;
    }
    panel_ministeps<NBCN,4>(rr, org, rowsN, tid, lane, wid,
                            redrowL, jrowL, redvL, rediL, redoL, jorgL);
    if (tid < rowsN){
      #pragma unroll
      for (int c = 0; c < NBCN; ++c) stage[NBC + tid][c] = rr[c];
      permbuf[b*(NPAN*NA) + (pidx+1)*NA + tid] = org;
    }
    __syncthreads();
    if (NBCN == NB){
      for (int idx = tid; idx < rowsN*8; idx += 256){
        int i = idx >> 3, q = idx & 7;
        *(float4*)(Ab + (size_t)(k0n+i)*APITCH + k0n + 4*q) =
          *(const float4*)&stage[NBC + i][4*q];
      }
    } else {
      for (int idx = tid; idx < rowsN*NBCN; idx += 256){
        int i = idx / NBCN, c = idx - i*NBCN;
        Ab[(size_t)(k0n+i)*APITCH + k0n + c] = stage[NBC + i][c];
      }
    }
  }
}

// ---------------------------------------------------------------------------
// Kernel 2c: back-substitution, right-looking, LDS-resident t-vector.
// One block per batch, 512 threads. Per block-step: stage U11 (coalesced),
// wave0 trisolve from LDS, then rank-nb update of ALL rows above with
// coalesced float4 reads (8 lanes per row) + shfl reduce.
// ---------------------------------------------------------------------------
__global__ __launch_bounds__(512) void backsub_kernel(const float* __restrict__ A,
                                                      float* __restrict__ wv){
  const int b = blockIdx.x;
  const float* Ab = A + (size_t)b*NA*APITCH;
  const int tid  = threadIdx.x;
  const int lane = tid & 63;
  const int wid  = tid >> 6;

  __shared__ float t2[NA][2];
  __shared__ float xs[NA][2];
  __shared__ float u11[NB][NB+1];

  for (int i = tid; i < NA; i += 512){
    t2[i][0] = Ab[(size_t)i*APITCH + NA];
    t2[i][1] = Ab[(size_t)i*APITCH + NA + 1];
  }
  __syncthreads();

  for (int bp = NPAN-1; bp >= 0; --bp){
    const int k0 = bp*NB;
    const int nb = (NA - k0 < NB) ? (NA - k0) : NB;

    // stage U11 (coalesced rows)
    for (int idx = tid; idx < nb*nb; idx += 512){
      int r = idx / nb, c = idx - r*nb;
      u11[r][c] = Ab[(size_t)(k0+r)*APITCH + k0 + c];
    }
    __syncthreads();

    // wave0: nb x nb triangular solve, lane = row*2 + channel
    if (wid == 0){
      int j = lane >> 1, ch = lane & 1;
      float tval = (j < nb) ? t2[k0+j][ch] : 0.0f;
      for (int k = nb-1; k >= 0; --k){
        float tk = __shfl(tval, 2*k + ch);
        float xk = tk / u11[k][k];
        if (j <  k) tval = fmaf(-u11[j][k], xk, tval);
        if (j == k) tval = xk;
      }
      if (j < nb) xs[k0+j][ch] = tval;
    }
    __syncthreads();

    // rank-nb update of rows [0, k0): t2[i] -= U[i, k0:k0+nb] . x
    if (nb == NB){
      const int q = tid & 7;
      for (int base = 0; base < k0; base += 64){
        const int i = base + (tid >> 3);
        float px = 0.0f, py = 0.0f;
        if (i < k0){
          float4 v = *(const float4*)(Ab + (size_t)i*APITCH + k0 + 4*q);
          px = v.x*xs[k0+4*q+0][0] + v.y*xs[k0+4*q+1][0]
             + v.z*xs[k0+4*q+2][0] + v.w*xs[k0+4*q+3][0];
          py = v.x*xs[k0+4*q+0][1] + v.y*xs[k0+4*q+1][1]
             + v.z*xs[k0+4*q+2][1] + v.w*xs[k0+4*q+3][1];
        }
        px += __shfl_xor(px, 1); px += __shfl_xor(px, 2); px += __shfl_xor(px, 4);
        py += __shfl_xor(py, 1); py += __shfl_xor(py, 2); py += __shfl_xor(py, 4);
        if (q == 0 && i < k0){
          t2[i][0] -= px;
          t2[i][1] -= py;
        }
      }
    } else {
      for (int i = tid; i < k0; i += 512){
        float s0 = 0.0f, s1 = 0.0f;
        #pragma unroll
        for (int m = 0; m < 3; ++m){
          float u = Ab[(size_t)i*APITCH + k0 + m];
          s0 = fmaf(u, xs[k0+m][0], s0);
          s1 = fmaf(u, xs[k0+m][1], s1);
        }
        t2[i][0] -= s0;
        t2[i][1] -= s1;
      }
    }
    __syncthreads();
  }

  for (int i = tid; i < NA; i += 512){
    wv[((size_t)b*NA + i)*2 + 0] = xs[i][0];
    wv[((size_t)b*NA + i)*2 + 1] = xs[i][1];
  }
}

// ---------------------------------------------------------------------------
// Kernel 3: evaluate the warp on the s x s grid.
// ---------------------------------------------------------------------------
__global__ __launch_bounds__(256) void eval_kernel(const float* __restrict__ src,
                                                   const float* __restrict__ wv,
                                                   float* __restrict__ out){
  const int b  = blockIdx.x >> 8;
  const int yi = blockIdx.x & 255;
  const int xi = threadIdx.x;
  __shared__ float2 sxy[NCTRL], wxy[NCTRL];
  const float* sb = src + b*NCTRL*2;
  const float* wb = wv + (size_t)b*NA*2;
  sxy[xi] = ((const float2*)sb)[xi];
  wxy[xi] = ((const float2*)wb)[xi];
  __syncthreads();

  const float step = 2.0f/255.0f;
  const float gx = -1.0f + step*(float)xi;
  const float gy = -1.0f + step*(float)yi;

  float accx = wb[512] + wb[514]*gx + wb[516]*gy;
  float accy = wb[513] + wb[515]*gx + wb[517]*gy;

  #pragma unroll 8
  for (int j = 0; j < NCTRL; ++j){
    float2 s = sxy[j];
    float2 w = wxy[j];
    float dx = gx - s.x;
    float dy = gy - s.y;
    float r = sqrtf(fmaf(dx, dx, dy*dy));
    accx = fmaf(r, w.x, accx);
    accy = fmaf(r, w.y, accy);
  }
  out[((size_t)(b*2    )*SGRID + yi)*SGRID + xi] = accx;
  out[((size_t)(b*2 + 1)*SGRID + yi)*SGRID + xi] = accy;
}

// ---------------------------------------------------------------------------
extern "C" void kernel_launch(void* const* d_in, const int* in_sizes, int n_in,
                              void* d_out, int out_size, void* d_ws, size_t ws_size,
                              hipStream_t stream) {
  const float* src = (const float*)d_in[0];
  const float* dst = (const float*)d_in[1];
  float* out = (float*)d_out;

  const size_t matElems = (size_t)BATCH*NA*APITCH;
  float* A     = (float*)d_ws;
  float* wv    = A + matElems;
  int*   permb = (int*)(wv + (size_t)BATCH*NA*2);

  build_kernel<<<BATCH*13, 256, 0, stream>>>(src, dst, A);

  // p = 0: standalone panel
  panel_kernel<NB><<<BATCH, 320, 0, stream>>>(A, permb, 0, 0);

  // p = 0..6: update + lookahead factorization of panel p+1 (width 32)
  for (int p = 0; p <= 6; ++p){
    const int k0 = p*NB;
    const int tc = NAUG - (k0 + NB);
    const int sb = (tc + 31) >> 5;
    update_kernel<NB, NB, true><<<BATCH*sb, 256, 0, stream>>>(A, permb, k0, p, sb);
  }
  // p = 7: update (1 strip) + lookahead of tail panel (width 3)
  update_kernel<NB, 3, true><<<BATCH, 256, 0, stream>>>(A, permb, 7*NB, 7, 1);
  // p = 8: final TRSM of the 2 rhs columns against the 3x3 tail
  update_kernel<3, 3, false><<<BATCH, 256, 0, stream>>>(A, permb, 8*NB, 8, 1);

  backsub_kernel<<<BATCH, 512, 0, stream>>>(A, wv);
  eval_kernel<<<BATCH*SGRID, 256, 0, stream>>>(src, wv, out);
}